// Round 1
// baseline (7773.655 us; speedup 1.0000x reference)
//
#include <hip/hip_runtime.h>
#include <cstdint>

// ---------------------------------------------------------------------------
// LSTMdecoder: attention (emb->proj->scores->softmax->context->proj) feeding a
// 2-layer LSTM over 256 timesteps. All GEMMs in bf16 MFMA (fp32 acc), gate
// math + cell state in fp32. Sequential part = one persistent kernel with a
// device-scope barrier per pipelined phase (257 phases, 1 barrier each).
// Workspace use ~147 MB.
// ---------------------------------------------------------------------------

typedef unsigned short u16;
typedef __attribute__((ext_vector_type(8))) short short8;   // 8 x bf16 bits
typedef __attribute__((ext_vector_type(4))) short short4v;  // 4 x bf16 bits
typedef __attribute__((ext_vector_type(4))) float f32x4;

__device__ __forceinline__ u16 f2bf(float f) {
  union { float f; unsigned u; } v; v.f = f;
  unsigned r = v.u + 0x7fffu + ((v.u >> 16) & 1u);  // RNE
  return (u16)(r >> 16);
}

__device__ __forceinline__ float sigm(float x) { return 1.f / (1.f + __expf(-x)); }
__device__ __forceinline__ float tanh_fast(float x) {
  float e = __expf(-2.f * fabsf(x));
  float t = (1.f - e) / (1.f + e);
  return x < 0.f ? -t : t;
}

// --------------------------- elementwise f32 -> bf16 ------------------------
__global__ void conv_kernel(const float* __restrict__ in, u16* __restrict__ out, long n) {
  long i = ((long)blockIdx.x * 256 + threadIdx.x) * 4;
  if (i < n) {
    float4 v = *(const float4*)(in + i);
    union { short4v s4; u16 s[4]; } pk;
    pk.s[0] = f2bf(v.x); pk.s[1] = f2bf(v.y); pk.s[2] = f2bf(v.z); pk.s[3] = f2bf(v.w);
    *(short4v*)(out + i) = pk.s4;
  }
}

// --------------------- transpose + convert: f32[K][N] -> bf16[N][K] ---------
__global__ void tconv_kernel(const float* __restrict__ in, u16* __restrict__ out,
                             int K, int N, long sIn, long sOut) {
  __shared__ float tile[32][33];
  const int z = blockIdx.z;
  in += (long)z * sIn; out += (long)z * sOut;
  const int nt = blockIdx.x * 32, kt = blockIdx.y * 32;
  const int tx = threadIdx.x & 31, ty = (threadIdx.x >> 5) * 4;
#pragma unroll
  for (int r = 0; r < 4; ++r)
    tile[ty + r][tx] = in[(long)(kt + ty + r) * N + nt + tx];
  __syncthreads();
#pragma unroll
  for (int r = 0; r < 4; ++r)
    out[(long)(nt + ty + r) * K + kt + tx] = f2bf(tile[tx][ty + r]);
}

// --------------------------- bfold = din_b @ k0 + b0 ------------------------
__global__ void bfold_kernel(const float* __restrict__ din_b, const float* __restrict__ k0,
                             const float* __restrict__ b0, float* __restrict__ bf) {
  int n = blockIdx.x * 256 + threadIdx.x;  // 0..2047
  float acc = b0[n];
  for (int k = 0; k < 512; ++k) acc += din_b[k] * k0[(long)k * 2048 + n];
  bf[n] = acc;
}

// ------------------- softmax over rows of 512 (one wave per row) ------------
__global__ __launch_bounds__(256) void softmax_kernel(const float* __restrict__ in,
                                                      u16* __restrict__ out) {
  const int row = blockIdx.x * 4 + (threadIdx.x >> 6);
  const int lane = threadIdx.x & 63;
  const float* p = in + (long)row * 512 + lane * 8;
  float4 a = *(const float4*)p, b = *(const float4*)(p + 4);
  float v[8] = {a.x, a.y, a.z, a.w, b.x, b.y, b.z, b.w};
  float m = v[0];
#pragma unroll
  for (int i = 1; i < 8; ++i) m = fmaxf(m, v[i]);
  for (int o = 32; o > 0; o >>= 1) m = fmaxf(m, __shfl_xor(m, o));
  float s = 0.f;
#pragma unroll
  for (int i = 0; i < 8; ++i) { v[i] = __expf(v[i] - m); s += v[i]; }
  for (int o = 32; o > 0; o >>= 1) s += __shfl_xor(s, o);
  const float inv = 1.f / s;
  union { short8 v8; u16 s2[8]; } pk;
#pragma unroll
  for (int i = 0; i < 8; ++i) pk.s2[i] = f2bf(v[i] * inv);
  *(short8*)(out + (long)row * 512 + lane * 8) = pk.v8;
}

// ---------------------------------------------------------------------------
// Generic "BT" MFMA GEMM: C[m][n] = sum_k A[m][k] * B[n][k]  (both K-contig)
// 128x128 tile, BK=32, 256 threads (4 waves -> 64x64 quadrants of 4x4 MFMA).
// STAGEA: 0 = A is bf16 [m][k]; 1 = A rows gathered from f32 emb + converted.
// EPI:    0 = bf16 store (+bias), 1 = f32 store (+bias),
//         2 = f32 store with mask*-1e9 fused, 3 = bf16 store transposed C[n][m]
// ---------------------------------------------------------------------------
template <int STAGEA, int EPI, bool HASBIAS>
__global__ __launch_bounds__(256, 2) void gemm_bt_kernel(
    const u16* __restrict__ Ab, const float* __restrict__ Af,
    const u16* __restrict__ Bb,
    float* __restrict__ Cf, u16* __restrict__ Cb,
    const float* __restrict__ bias, const int* __restrict__ gather,
    const int* __restrict__ mask, int maskld,
    int M, int N, int K, long sA, long sB, long sC, long sMask) {
  constexpr int BM = 128, BK = 32, LDST = 40;  // +8 pad -> conflict-free frag reads
  __shared__ u16 As[BM * LDST];
  __shared__ u16 Bs[BM * LDST];
  const int z = blockIdx.z;
  const int m0 = blockIdx.y * BM, n0 = blockIdx.x * BM;
  const int t = threadIdx.x;
  const int trow = t >> 2, tkc = t & 3;
  const int wid = t >> 6, lane = t & 63;
  const int mq = (wid & 1) * 64, nq = (wid >> 1) * 64;
  const int fr = lane & 15;
  const int fko = (lane >> 4) * 8;

  const u16* Bbz = Bb + (long)z * sB;
  const u16* bptr0 = Bbz + (long)(n0 + trow) * K + tkc * 8;
  const u16* bptr1 = bptr0 + (long)64 * K;

  const u16* aptr0 = nullptr; const u16* aptr1 = nullptr;
  const float* gptr0 = nullptr; const float* gptr1 = nullptr;
  if (STAGEA == 0) {
    const u16* Abz = Ab + (long)z * sA;
    aptr0 = Abz + (long)(m0 + trow) * K + tkc * 8;
    aptr1 = aptr0 + (long)64 * K;
  } else {
    int g0 = gather[m0 + trow];
    int g1 = gather[m0 + 64 + trow];
    gptr0 = Af + (long)g0 * K + tkc * 8;
    gptr1 = Af + (long)g1 * K + tkc * 8;
  }

  const f32x4 z4 = {0.f, 0.f, 0.f, 0.f};
  f32x4 acc[4][4];
#pragma unroll
  for (int i = 0; i < 4; ++i)
#pragma unroll
    for (int j = 0; j < 4; ++j) acc[i][j] = z4;

  u16* asw0 = &As[trow * LDST + tkc * 8];
  u16* asw1 = &As[(64 + trow) * LDST + tkc * 8];
  u16* bsw0 = &Bs[trow * LDST + tkc * 8];
  u16* bsw1 = &Bs[(64 + trow) * LDST + tkc * 8];

  for (int k0 = 0; k0 < K; k0 += BK) {
    if (STAGEA == 0) {
      *(short8*)asw0 = *(const short8*)(aptr0 + k0);
      *(short8*)asw1 = *(const short8*)(aptr1 + k0);
    } else {
      float4 u0 = *(const float4*)(gptr0 + k0);
      float4 u1 = *(const float4*)(gptr0 + k0 + 4);
      union { short8 v; u16 s[8]; } pk;
      pk.s[0] = f2bf(u0.x); pk.s[1] = f2bf(u0.y); pk.s[2] = f2bf(u0.z); pk.s[3] = f2bf(u0.w);
      pk.s[4] = f2bf(u1.x); pk.s[5] = f2bf(u1.y); pk.s[6] = f2bf(u1.z); pk.s[7] = f2bf(u1.w);
      *(short8*)asw0 = pk.v;
      float4 w0 = *(const float4*)(gptr1 + k0);
      float4 w1 = *(const float4*)(gptr1 + k0 + 4);
      pk.s[0] = f2bf(w0.x); pk.s[1] = f2bf(w0.y); pk.s[2] = f2bf(w0.z); pk.s[3] = f2bf(w0.w);
      pk.s[4] = f2bf(w1.x); pk.s[5] = f2bf(w1.y); pk.s[6] = f2bf(w1.z); pk.s[7] = f2bf(w1.w);
      *(short8*)asw1 = pk.v;
    }
    *(short8*)bsw0 = *(const short8*)(bptr0 + k0);
    *(short8*)bsw1 = *(const short8*)(bptr1 + k0);
    __syncthreads();
    short8 afr[4], bfr[4];
#pragma unroll
    for (int i = 0; i < 4; ++i) afr[i] = *(const short8*)&As[(mq + i * 16 + fr) * LDST + fko];
#pragma unroll
    for (int j = 0; j < 4; ++j) bfr[j] = *(const short8*)&Bs[(nq + j * 16 + fr) * LDST + fko];
#pragma unroll
    for (int i = 0; i < 4; ++i)
#pragma unroll
      for (int j = 0; j < 4; ++j)
        acc[i][j] = __builtin_amdgcn_mfma_f32_16x16x32_bf16(afr[i], bfr[j], acc[i][j], 0, 0, 0);
    __syncthreads();
  }

  // epilogue: C row = m (A side), col = n (B side); col=lane&15, row=(lane>>4)*4+reg
  const int r4b = (lane >> 4) * 4;
#pragma unroll
  for (int j = 0; j < 4; ++j) {
    const int n = n0 + nq + j * 16 + fr;
    float bv = 0.f;
    if (HASBIAS) bv = bias[n];
#pragma unroll
    for (int i = 0; i < 4; ++i) {
      const int mb = m0 + mq + i * 16 + r4b;
      if (EPI == 0) {
#pragma unroll
        for (int r = 0; r < 4; ++r)
          Cb[(long)z * sC + (long)(mb + r) * N + n] = f2bf(acc[i][j][r] + bv);
      } else if (EPI == 1) {
#pragma unroll
        for (int r = 0; r < 4; ++r)
          Cf[(long)z * sC + (long)(mb + r) * N + n] = acc[i][j][r] + bv;
      } else if (EPI == 2) {
#pragma unroll
        for (int r = 0; r < 4; ++r) {
          float mv = (float)mask[(long)z * sMask + (long)n * maskld + (mb + r)];
          Cf[(long)z * sC + (long)(mb + r) * N + n] = acc[i][j][r] + mv * -1e9f;
        }
      } else {  // EPI 3: transposed bf16 C[n][m]
        union { short4v v; u16 s[4]; } pk2;
#pragma unroll
        for (int r = 0; r < 4; ++r) pk2.s[r] = f2bf(acc[i][j][r]);
        *(short4v*)&Cb[(long)n * M + mb] = pk2.v;
      }
    }
  }
}

// ---------------------------------------------------------------------------
// Persistent 2-layer LSTM. 128 blocks x 256 threads. Pipelined: phase t does
// layer0 step t (blocks 0..63) and layer1 step t-1 (blocks 64..127); both read
// h0(t-1). One device barrier per phase. Gate g = wave id; cell state lives in
// wave0 registers (C-frag layout). h exchanged via double-buffered bf16 bufs.
// ---------------------------------------------------------------------------
__global__ __launch_bounds__(256, 1) void lstm_kernel(
    const u16* __restrict__ wt_r0, const u16* __restrict__ wt_k1,
    const u16* __restrict__ wt_r1, const float* __restrict__ xk0,
    const float* __restrict__ b1, u16* __restrict__ h0b, u16* __restrict__ h1b,
    float* __restrict__ out, int* bar) {
  __shared__ float zs[3][4][64];
  const int bid = blockIdx.x;
  const bool isL1 = bid >= 64;
  const int tid2 = isL1 ? bid - 64 : bid;
  const int mtile = tid2 & 1;   // b block: 0 -> b 0..15, 1 -> b 16..31
  const int grp = tid2 >> 1;    // u block: 16 units each, 0..31
  const int wid = threadIdx.x >> 6, lane = threadIdx.x & 63;
  const int fr = lane & 15;
  const int fko = (lane >> 4) * 8;
  const int r4b = (lane >> 4) * 4;
  const int col = wid * 512 + grp * 16 + fr;  // gate column (i,f,g,o blocks)
  const int am = mtile * 16 + fr;             // A row (batch)
  const int u = grp * 16 + fr;                // unit index
  const u16* wrowA = (isL1 ? wt_k1 : wt_r0) + (long)col * 512 + fko;
  const u16* wrowB = wt_r1 + (long)col * 512 + fko;
  float cst[4] = {0.f, 0.f, 0.f, 0.f};
  float bl[4] = {0.f, 0.f, 0.f, 0.f};
  if (isL1) { bl[0] = b1[u]; bl[1] = b1[512 + u]; bl[2] = b1[1024 + u]; bl[3] = b1[1536 + u]; }

#pragma unroll 1
  for (int t = 0; t <= 256; ++t) {
    const int rd = (t + 1) & 1, wr = t & 1;
    const bool active = isL1 ? (t >= 1) : (t < 256);
    f32x4 acc = {0.f, 0.f, 0.f, 0.f};
    float xadd[4][4];
    if (active) {
      const u16* h0p = h0b + rd * (32 * 512);
      if (!isL1) {
#pragma unroll
        for (int r = 0; r < 4; ++r) {
          const float* xp = xk0 + ((long)(mtile * 16 + r4b + r) * 256 + t) * 2048 + u;
          xadd[r][0] = xp[0]; xadd[r][1] = xp[512]; xadd[r][2] = xp[1024]; xadd[r][3] = xp[1536];
        }
        const u16* arow = h0p + (long)am * 512 + fko;
#pragma unroll
        for (int ks = 0; ks < 16; ++ks) {
          short8 a = *(const short8*)(arow + ks * 32);
          short8 b = *(const short8*)(wrowA + ks * 32);
          acc = __builtin_amdgcn_mfma_f32_16x16x32_bf16(a, b, acc, 0, 0, 0);
        }
      } else {
        const u16* h1p = h1b + rd * (32 * 512);
        const u16* arow0 = h0p + (long)am * 512 + fko;
        const u16* arow1 = h1p + (long)am * 512 + fko;
#pragma unroll
        for (int ks = 0; ks < 16; ++ks) {
          short8 a = *(const short8*)(arow0 + ks * 32);
          short8 b = *(const short8*)(wrowA + ks * 32);
          acc = __builtin_amdgcn_mfma_f32_16x16x32_bf16(a, b, acc, 0, 0, 0);
          short8 a2 = *(const short8*)(arow1 + ks * 32);
          short8 b2 = *(const short8*)(wrowB + ks * 32);
          acc = __builtin_amdgcn_mfma_f32_16x16x32_bf16(a2, b2, acc, 0, 0, 0);
        }
      }
      if (wid > 0) {
#pragma unroll
        for (int r = 0; r < 4; ++r) zs[wid - 1][r][lane] = acc[r];
      }
    }
    __syncthreads();
    if (active && wid == 0) {
      const int tt = isL1 ? t - 1 : t;
#pragma unroll
      for (int r = 0; r < 4; ++r) {
        const int b = mtile * 16 + r4b + r;
        float zi = acc[r];
        float zf = zs[0][r][lane];
        float zg = zs[1][r][lane];
        float zo = zs[2][r][lane];
        if (!isL1) { zi += xadd[r][0]; zf += xadd[r][1]; zg += xadd[r][2]; zo += xadd[r][3]; }
        else       { zi += bl[0]; zf += bl[1]; zg += bl[2]; zo += bl[3]; }
        float cn = sigm(zf) * cst[r] + sigm(zi) * tanh_fast(zg);
        cst[r] = cn;
        float h = sigm(zo) * tanh_fast(cn);
        if (!isL1) {
          h0b[wr * (32 * 512) + b * 512 + u] = f2bf(h);
        } else {
          h1b[wr * (32 * 512) + b * 512 + u] = f2bf(h);
          out[((long)b * 256 + tt) * 512 + u] = h;
        }
      }
    }
    if (t < 256) {
      __threadfence();      // drain our global writes (release side)
      __syncthreads();      // all lanes' fences done before arrival
      if (threadIdx.x == 0) {
        int old = __hip_atomic_fetch_add(&bar[0], 1, __ATOMIC_ACQ_REL, __HIP_MEMORY_SCOPE_AGENT);
        if (old == 128 * (t + 1) - 1) {
          __hip_atomic_store(&bar[16], t + 1, __ATOMIC_RELEASE, __HIP_MEMORY_SCOPE_AGENT);
        } else {
          while (__hip_atomic_load(&bar[16], __ATOMIC_RELAXED, __HIP_MEMORY_SCOPE_AGENT) < t + 1)
            __builtin_amdgcn_s_sleep(8);
        }
      }
      __syncthreads();
      __threadfence();      // acquire side: invalidate L1 so fresh h-bufs are read
    }
  }
}

// ---------------------------------------------------------------------------
extern "C" void kernel_launch(void* const* d_in, const int* in_sizes, int n_in,
                              void* d_out, int out_size, void* d_ws, size_t ws_size,
                              hipStream_t stream) {
  (void)in_sizes; (void)n_in; (void)out_size; (void)ws_size;
  const float* enc   = (const float*)d_in[0];
  const int*   lw    = (const int*)d_in[1];
  const int*   mask  = (const int*)d_in[2];
  const float* P_w   = (const float*)d_in[3];
  const float* P_b   = (const float*)d_in[4];
  const float* emb   = (const float*)d_in[5];
  const float* din_w = (const float*)d_in[6];
  const float* din_b = (const float*)d_in[7];
  const float* k0    = (const float*)d_in[8];
  const float* r0    = (const float*)d_in[9];
  const float* b0    = (const float*)d_in[10];
  const float* k1    = (const float*)d_in[11];
  const float* r1    = (const float*)d_in[12];
  const float* b1    = (const float*)d_in[13];
  float* out = (float*)d_out;

  char* base = (char*)d_ws;
  size_t off = 0;
  auto alloc = [&](size_t b) -> void* {
    void* p = base + off;
    off = (off + b + 255) & ~(size_t)255;
    return p;
  };
  float* xk0  = (float*)alloc(8192UL * 2048 * 4);   // 67 MB
  u16* encb   = (u16*)alloc(32UL * 512 * 512 * 2);  // enc bf16 [b][e][d]
  u16* encT   = (u16*)alloc(32UL * 512 * 512 * 2);  // enc bf16 [b][d][e]
  float* aTf  = (float*)alloc(32UL * 256 * 512 * 4);// scores [b][s][e] f32
  u16* aTb    = (u16*)alloc(32UL * 256 * 512 * 2);  // softmaxed scores bf16
  u16* pd     = (u16*)alloc(8192UL * 512 * 2);      // py, later dec (bf16)
  u16* wt_r0  = (u16*)alloc(2048UL * 512 * 2);
  u16* wt_k1  = (u16*)alloc(2048UL * 512 * 2);
  u16* wt_r1  = (u16*)alloc(2048UL * 512 * 2);
  u16* k0T    = (u16*)alloc(2048UL * 512 * 2);
  u16* PwT    = (u16*)alloc(512UL * 512 * 2);
  u16* dinwb  = (u16*)alloc(512UL * 512 * 2);
  u16* WfT    = (u16*)alloc(2048UL * 512 * 2);      // (din_w@k0)^T bf16
  float* bfld = (float*)alloc(2048 * 4);
  u16* h0b    = (u16*)alloc(2UL * 32 * 512 * 2);    // 64 KB
  u16* h1b    = (u16*)alloc(2UL * 32 * 512 * 2);    // 64 KB
  int* bar    = (int*)alloc(4096);

  // --- prep: converts / transposes (all bf16 targets) ---
  conv_kernel<<<8192, 256, 0, stream>>>(enc, encb, 32L * 512 * 512);
  tconv_kernel<<<dim3(16, 16, 32), 256, 0, stream>>>(enc, encT, 512, 512, 262144, 262144);
  tconv_kernel<<<dim3(64, 16, 1), 256, 0, stream>>>(r0, wt_r0, 512, 2048, 0, 0);
  tconv_kernel<<<dim3(64, 16, 1), 256, 0, stream>>>(k1, wt_k1, 512, 2048, 0, 0);
  tconv_kernel<<<dim3(64, 16, 1), 256, 0, stream>>>(r1, wt_r1, 512, 2048, 0, 0);
  tconv_kernel<<<dim3(64, 16, 1), 256, 0, stream>>>(k0, k0T, 512, 2048, 0, 0);
  tconv_kernel<<<dim3(16, 16, 1), 256, 0, stream>>>(P_w, PwT, 512, 512, 0, 0);
  conv_kernel<<<256, 256, 0, stream>>>(din_w, dinwb, 512L * 512);

  // K1: py = emb[lw] @ P_w + P_b   (M=8192, N=512, K=512) -> pd (bf16)
  gemm_bt_kernel<1, 0, true><<<dim3(4, 64, 1), 256, 0, stream>>>(
      nullptr, emb, PwT, nullptr, pd, P_b, lw, nullptr, 0,
      8192, 512, 512, 0, 0, 0, 0);
  // K5: WfT = (din_w @ k0)^T  (M=512, N=2048, K=512)
  gemm_bt_kernel<0, 3, false><<<dim3(16, 4, 1), 256, 0, stream>>>(
      dinwb, nullptr, k0T, nullptr, WfT, nullptr, nullptr, nullptr, 0,
      512, 2048, 512, 0, 0, 0, 0);
  bfold_kernel<<<8, 256, 0, stream>>>(din_b, k0, b0, bfld);
  // K2: aTf[b][s][e] = py[b,s,:]·enc[b,e,:] + mask[b,e,s]*-1e9
  gemm_bt_kernel<0, 2, false><<<dim3(4, 2, 32), 256, 0, stream>>>(
      pd, nullptr, encb, aTf, nullptr, nullptr, nullptr, mask, 256,
      256, 512, 512, 131072, 262144, 131072, 131072);
  // K3: softmax over e (rows of 512) -> aTb bf16
  softmax_kernel<<<2048, 256, 0, stream>>>(aTf, aTb);
  // K4: dec[b][s][d] = sum_e aT[s,e] * enc[e,d]  -> pd (bf16, overwrites py)
  gemm_bt_kernel<0, 0, false><<<dim3(4, 2, 32), 256, 0, stream>>>(
      aTb, nullptr, encT, nullptr, pd, nullptr, nullptr, nullptr, 0,
      256, 512, 512, 131072, 262144, 131072, 0);
  // K6: xk0 = dec @ Wf + bfold  (M=8192, N=2048, K=512) -> f32
  gemm_bt_kernel<0, 1, true><<<dim3(16, 64, 1), 256, 0, stream>>>(
      pd, nullptr, WfT, xk0, nullptr, bfld, nullptr, nullptr, 0,
      8192, 2048, 512, 0, 0, 0, 0);

  // zero h buffers + barrier state (re-zeroed every call: graph-safe)
  hipMemsetAsync(h0b, 0, 65536 + 65536 + 4096, stream);
  // persistent sequential LSTM (257 pipelined phases, 1 barrier each)
  lstm_kernel<<<128, 256, 0, stream>>>(wt_r0, wt_k1, wt_r1, xk0, b1, h0b, h1b, out, bar);
}

// Round 2
// 1619.736 us; speedup vs baseline: 4.7993x; 4.7993x over previous
//
#include <hip/hip_runtime.h>
#include <cstdint>

// ---------------------------------------------------------------------------
// LSTMdecoder: attention (emb->proj->scores->softmax->context->proj) feeding a
// 2-layer LSTM over 256 timesteps. All GEMMs bf16 MFMA (fp32 acc), gate math
// + cell state fp32. Sequential part = persistent kernel, 128 blocks, one
// contention-free distributed barrier per pipelined phase (258 phases).
// Weights for the recurrent GEMMs live in VGPRs; h-state crosses blocks via
// agent-scope (sc1) atomics, no fences.
// ---------------------------------------------------------------------------

typedef unsigned short u16;
typedef unsigned long long u64;
typedef __attribute__((ext_vector_type(8))) short short8;   // 8 x bf16 bits
typedef __attribute__((ext_vector_type(4))) short short4v;  // 4 x bf16 bits
typedef __attribute__((ext_vector_type(4))) float f32x4;

__device__ __forceinline__ u16 f2bf(float f) {
  union { float f; unsigned u; } v; v.f = f;
  unsigned r = v.u + 0x7fffu + ((v.u >> 16) & 1u);  // RNE
  return (u16)(r >> 16);
}

__device__ __forceinline__ float sigm(float x) { return 1.f / (1.f + __expf(-x)); }
__device__ __forceinline__ float tanh_fast(float x) {
  float e = __expf(-2.f * fabsf(x));
  float t = (1.f - e) / (1.f + e);
  return x < 0.f ? -t : t;
}

// --------------------------- elementwise f32 -> bf16 ------------------------
__global__ void conv_kernel(const float* __restrict__ in, u16* __restrict__ out, long n) {
  long i = ((long)blockIdx.x * 256 + threadIdx.x) * 4;
  if (i < n) {
    float4 v = *(const float4*)(in + i);
    union { short4v s4; u16 s[4]; } pk;
    pk.s[0] = f2bf(v.x); pk.s[1] = f2bf(v.y); pk.s[2] = f2bf(v.z); pk.s[3] = f2bf(v.w);
    *(short4v*)(out + i) = pk.s4;
  }
}

// --------------------- transpose + convert: f32[K][N] -> bf16[N][K] ---------
__global__ void tconv_kernel(const float* __restrict__ in, u16* __restrict__ out,
                             int K, int N, long sIn, long sOut) {
  __shared__ float tile[32][33];
  const int z = blockIdx.z;
  in += (long)z * sIn; out += (long)z * sOut;
  const int nt = blockIdx.x * 32, kt = blockIdx.y * 32;
  const int tx = threadIdx.x & 31, ty = (threadIdx.x >> 5) * 4;
#pragma unroll
  for (int r = 0; r < 4; ++r)
    tile[ty + r][tx] = in[(long)(kt + ty + r) * N + nt + tx];
  __syncthreads();
#pragma unroll
  for (int r = 0; r < 4; ++r)
    out[(long)(nt + ty + r) * K + kt + tx] = f2bf(tile[tx][ty + r]);
}

// --------------------------- bfold = din_b @ k0 + b0 ------------------------
__global__ void bfold_kernel(const float* __restrict__ din_b, const float* __restrict__ k0,
                             const float* __restrict__ b0, float* __restrict__ bf) {
  int n = blockIdx.x * 256 + threadIdx.x;  // 0..2047
  float acc = b0[n];
  for (int k = 0; k < 512; ++k) acc += din_b[k] * k0[(long)k * 2048 + n];
  bf[n] = acc;
}

// ------------------- softmax over rows of 512 (one wave per row) ------------
__global__ __launch_bounds__(256) void softmax_kernel(const float* __restrict__ in,
                                                      u16* __restrict__ out) {
  const int row = blockIdx.x * 4 + (threadIdx.x >> 6);
  const int lane = threadIdx.x & 63;
  const float* p = in + (long)row * 512 + lane * 8;
  float4 a = *(const float4*)p, b = *(const float4*)(p + 4);
  float v[8] = {a.x, a.y, a.z, a.w, b.x, b.y, b.z, b.w};
  float m = v[0];
#pragma unroll
  for (int i = 1; i < 8; ++i) m = fmaxf(m, v[i]);
  for (int o = 32; o > 0; o >>= 1) m = fmaxf(m, __shfl_xor(m, o));
  float s = 0.f;
#pragma unroll
  for (int i = 0; i < 8; ++i) { v[i] = __expf(v[i] - m); s += v[i]; }
  for (int o = 32; o > 0; o >>= 1) s += __shfl_xor(s, o);
  const float inv = 1.f / s;
  union { short8 v8; u16 s2[8]; } pk;
#pragma unroll
  for (int i = 0; i < 8; ++i) pk.s2[i] = f2bf(v[i] * inv);
  *(short8*)(out + (long)row * 512 + lane * 8) = pk.v8;
}

// ---------------------------------------------------------------------------
// Generic "BT" MFMA GEMM: C[m][n] = sum_k A[m][k] * B[n][k]  (both K-contig)
// ---------------------------------------------------------------------------
template <int STAGEA, int EPI, bool HASBIAS>
__global__ __launch_bounds__(256, 2) void gemm_bt_kernel(
    const u16* __restrict__ Ab, const float* __restrict__ Af,
    const u16* __restrict__ Bb,
    float* __restrict__ Cf, u16* __restrict__ Cb,
    const float* __restrict__ bias, const int* __restrict__ gather,
    const int* __restrict__ mask, int maskld,
    int M, int N, int K, long sA, long sB, long sC, long sMask) {
  constexpr int BM = 128, BK = 32, LDST = 40;
  __shared__ u16 As[BM * LDST];
  __shared__ u16 Bs[BM * LDST];
  const int z = blockIdx.z;
  const int m0 = blockIdx.y * BM, n0 = blockIdx.x * BM;
  const int t = threadIdx.x;
  const int trow = t >> 2, tkc = t & 3;
  const int wid = t >> 6, lane = t & 63;
  const int mq = (wid & 1) * 64, nq = (wid >> 1) * 64;
  const int fr = lane & 15;
  const int fko = (lane >> 4) * 8;

  const u16* Bbz = Bb + (long)z * sB;
  const u16* bptr0 = Bbz + (long)(n0 + trow) * K + tkc * 8;
  const u16* bptr1 = bptr0 + (long)64 * K;

  const u16* aptr0 = nullptr; const u16* aptr1 = nullptr;
  const float* gptr0 = nullptr; const float* gptr1 = nullptr;
  if (STAGEA == 0) {
    const u16* Abz = Ab + (long)z * sA;
    aptr0 = Abz + (long)(m0 + trow) * K + tkc * 8;
    aptr1 = aptr0 + (long)64 * K;
  } else {
    int g0 = gather[m0 + trow];
    int g1 = gather[m0 + 64 + trow];
    gptr0 = Af + (long)g0 * K + tkc * 8;
    gptr1 = Af + (long)g1 * K + tkc * 8;
  }

  const f32x4 z4 = {0.f, 0.f, 0.f, 0.f};
  f32x4 acc[4][4];
#pragma unroll
  for (int i = 0; i < 4; ++i)
#pragma unroll
    for (int j = 0; j < 4; ++j) acc[i][j] = z4;

  u16* asw0 = &As[trow * LDST + tkc * 8];
  u16* asw1 = &As[(64 + trow) * LDST + tkc * 8];
  u16* bsw0 = &Bs[trow * LDST + tkc * 8];
  u16* bsw1 = &Bs[(64 + trow) * LDST + tkc * 8];

  for (int k0 = 0; k0 < K; k0 += BK) {
    if (STAGEA == 0) {
      *(short8*)asw0 = *(const short8*)(aptr0 + k0);
      *(short8*)asw1 = *(const short8*)(aptr1 + k0);
    } else {
      float4 u0 = *(const float4*)(gptr0 + k0);
      float4 u1 = *(const float4*)(gptr0 + k0 + 4);
      union { short8 v; u16 s[8]; } pk;
      pk.s[0] = f2bf(u0.x); pk.s[1] = f2bf(u0.y); pk.s[2] = f2bf(u0.z); pk.s[3] = f2bf(u0.w);
      pk.s[4] = f2bf(u1.x); pk.s[5] = f2bf(u1.y); pk.s[6] = f2bf(u1.z); pk.s[7] = f2bf(u1.w);
      *(short8*)asw0 = pk.v;
      float4 w0 = *(const float4*)(gptr1 + k0);
      float4 w1 = *(const float4*)(gptr1 + k0 + 4);
      pk.s[0] = f2bf(w0.x); pk.s[1] = f2bf(w0.y); pk.s[2] = f2bf(w0.z); pk.s[3] = f2bf(w0.w);
      pk.s[4] = f2bf(w1.x); pk.s[5] = f2bf(w1.y); pk.s[6] = f2bf(w1.z); pk.s[7] = f2bf(w1.w);
      *(short8*)asw1 = pk.v;
    }
    *(short8*)bsw0 = *(const short8*)(bptr0 + k0);
    *(short8*)bsw1 = *(const short8*)(bptr1 + k0);
    __syncthreads();
    short8 afr[4], bfr[4];
#pragma unroll
    for (int i = 0; i < 4; ++i) afr[i] = *(const short8*)&As[(mq + i * 16 + fr) * LDST + fko];
#pragma unroll
    for (int j = 0; j < 4; ++j) bfr[j] = *(const short8*)&Bs[(nq + j * 16 + fr) * LDST + fko];
#pragma unroll
    for (int i = 0; i < 4; ++i)
#pragma unroll
      for (int j = 0; j < 4; ++j)
        acc[i][j] = __builtin_amdgcn_mfma_f32_16x16x32_bf16(afr[i], bfr[j], acc[i][j], 0, 0, 0);
    __syncthreads();
  }

  const int r4b = (lane >> 4) * 4;
#pragma unroll
  for (int j = 0; j < 4; ++j) {
    const int n = n0 + nq + j * 16 + fr;
    float bv = 0.f;
    if (HASBIAS) bv = bias[n];
#pragma unroll
    for (int i = 0; i < 4; ++i) {
      const int mb = m0 + mq + i * 16 + r4b;
      if (EPI == 0) {
#pragma unroll
        for (int r = 0; r < 4; ++r)
          Cb[(long)z * sC + (long)(mb + r) * N + n] = f2bf(acc[i][j][r] + bv);
      } else if (EPI == 1) {
#pragma unroll
        for (int r = 0; r < 4; ++r)
          Cf[(long)z * sC + (long)(mb + r) * N + n] = acc[i][j][r] + bv;
      } else if (EPI == 2) {
#pragma unroll
        for (int r = 0; r < 4; ++r) {
          float mv = (float)mask[(long)z * sMask + (long)n * maskld + (mb + r)];
          Cf[(long)z * sC + (long)(mb + r) * N + n] = acc[i][j][r] + mv * -1e9f;
        }
      } else {
        union { short4v v; u16 s[4]; } pk2;
#pragma unroll
        for (int r = 0; r < 4; ++r) pk2.s[r] = f2bf(acc[i][j][r]);
        *(short4v*)&Cb[(long)n * M + mb] = pk2.v;
      }
    }
  }
}

// ---------------------------------------------------------------------------
// Persistent 2-layer LSTM. 128 blocks x 256 threads, pipelined (phase t:
// layer0 step t on blocks 0..63, layer1 step t-1 on blocks 64..127).
// Weights in VGPRs. h crosses blocks via agent-scope (sc1) atomics, staged
// through LDS. Barrier: per-block epoch slot (128B apart) + all-to-all poll
// by 128 threads -> no atomic RMW, no same-line contention, no fences.
// ---------------------------------------------------------------------------
__global__ __launch_bounds__(256, 1) void lstm_kernel(
    const u16* __restrict__ wt_r0, const u16* __restrict__ wt_k1,
    const u16* __restrict__ wt_r1, const float* __restrict__ xk0,
    const float* __restrict__ b1, u16* __restrict__ h0b, u16* __restrict__ h1b,
    float* __restrict__ out, int* __restrict__ slots) {
  constexpr int HST = 536;  // u16 row stride: 16B-aligned rows in LDS stage
  __shared__ u16 hst[2][16 * HST];   // 34.3 KB
  __shared__ float zs[3][4][64];     // 3 KB
  __shared__ u16 htile[16][16];      // 0.5 KB
  const int bid = blockIdx.x;
  const bool isL1 = bid >= 64;
  const int tid2 = isL1 ? bid - 64 : bid;
  const int mtile = tid2 & 1;   // batch half: rows mtile*16..+15
  const int grp = tid2 >> 1;    // 16-unit group, 0..31
  const int tid = threadIdx.x;
  const int wid = tid >> 6, lane = tid & 63;
  const int fr = lane & 15;
  const int fko = (lane >> 4) * 8;
  const int r4b = (lane >> 4) * 4;
  const int u = grp * 16 + fr;         // unit index
  const int col = wid * 512 + u;       // gate column (wave = gate i,f,g,o)

  // ---- weights into registers (loaded once; plain cached loads) ----
  short8 wA[16], wB[16];
  {
    const u16* wrowA = (isL1 ? wt_k1 : wt_r0) + (long)col * 512 + fko;
#pragma unroll
    for (int ks = 0; ks < 16; ++ks) wA[ks] = *(const short8*)(wrowA + ks * 32);
    if (isL1) {
      const u16* wrowB = wt_r1 + (long)col * 512 + fko;
#pragma unroll
      for (int ks = 0; ks < 16; ++ks) wB[ks] = *(const short8*)(wrowB + ks * 32);
    } else {
#pragma unroll
      for (int ks = 0; ks < 16; ++ks) wB[ks] = wA[ks];
    }
  }
  const float blw = isL1 ? b1[wid * 512 + u] : 0.f;
  float cst[4] = {0.f, 0.f, 0.f, 0.f};

  // stage-loader mapping: thread -> (row sr, 32-col chunk sc) of the 16x512 tile
  const int sr = tid >> 4;
  const int sc = (tid & 15) * 32;
  const long gbase = (long)(mtile * 16 + sr) * 512 + sc;

#pragma unroll 1
  for (int t = -1; t <= 256; ++t) {
    const bool act = isL1 ? (t >= 1) : (t >= 0 && t < 256);
    if (t < 0) {
      // zero-init: L0 blocks zero their h0b[buf1] tile; L1 zero h1b[buf0]
      if (wid == 0) {
        u16* dst = isL1 ? h1b : (h0b + 32 * 512);
        const int rr = lane >> 2, cc = (lane & 3) * 4;
        __hip_atomic_store((u64*)&dst[(mtile * 16 + rr) * 512 + grp * 16 + cc],
                           (u64)0, __ATOMIC_RELAXED, __HIP_MEMORY_SCOPE_AGENT);
        __builtin_amdgcn_s_waitcnt(0);
      }
    } else if (act) {
      const int rd = (t + 1) & 1;
      const u16* src0 = h0b + rd * (32 * 512);
#pragma unroll
      for (int j = 0; j < 8; ++j) {
        u64 v = __hip_atomic_load((const u64*)(src0 + gbase + j * 4),
                                  __ATOMIC_RELAXED, __HIP_MEMORY_SCOPE_AGENT);
        *(u64*)&hst[0][sr * HST + sc + j * 4] = v;
      }
      if (isL1) {
        const u16* src1 = h1b + rd * (32 * 512);
#pragma unroll
        for (int j = 0; j < 8; ++j) {
          u64 v = __hip_atomic_load((const u64*)(src1 + gbase + j * 4),
                                    __ATOMIC_RELAXED, __HIP_MEMORY_SCOPE_AGENT);
          *(u64*)&hst[1][sr * HST + sc + j * 4] = v;
        }
      }
    }
    __syncthreads();  // D: stage visible to all waves
    f32x4 acc = {0.f, 0.f, 0.f, 0.f};
    if (act && t >= 0) {
#pragma unroll
      for (int ks = 0; ks < 16; ++ks) {
        short8 a0 = *(const short8*)&hst[0][fr * HST + fko + ks * 32];
        acc = __builtin_amdgcn_mfma_f32_16x16x32_bf16(a0, wA[ks], acc, 0, 0, 0);
      }
      if (isL1) {
        f32x4 acc2 = {0.f, 0.f, 0.f, 0.f};
#pragma unroll
        for (int ks = 0; ks < 16; ++ks) {
          short8 a1 = *(const short8*)&hst[1][fr * HST + fko + ks * 32];
          acc2 = __builtin_amdgcn_mfma_f32_16x16x32_bf16(a1, wB[ks], acc2, 0, 0, 0);
        }
#pragma unroll
        for (int r = 0; r < 4; ++r) acc[r] += acc2[r] + blw;
      } else {
#pragma unroll
        for (int r = 0; r < 4; ++r)
          acc[r] += xk0[((long)(mtile * 16 + r4b + r) * 256 + t) * 2048 + col];
      }
      if (wid > 0) {
#pragma unroll
        for (int r = 0; r < 4; ++r) zs[wid - 1][r][lane] = acc[r];
      }
    }
    __syncthreads();  // A: zs visible to wave0
    if (act && t >= 0 && wid == 0) {
      const int tt = isL1 ? t - 1 : t;
#pragma unroll
      for (int r = 0; r < 4; ++r) {
        float zi = acc[r];
        float zf = zs[0][r][lane];
        float zg = zs[1][r][lane];
        float zo = zs[2][r][lane];
        float cn = sigm(zf) * cst[r] + sigm(zi) * tanh_fast(zg);
        cst[r] = cn;
        float h = sigm(zo) * tanh_fast(cn);
        htile[r4b + r][fr] = f2bf(h);
        if (isL1) out[((long)(mtile * 16 + r4b + r) * 256 + tt) * 512 + u] = h;
      }
      // repack via LDS -> 8B coherent stores (4 consecutive units per store)
      const int wr = t & 1;
      u16* dst = (isL1 ? h1b : h0b) + wr * (32 * 512);
      const int rr = lane >> 2, cc = (lane & 3) * 4;
      u64 v = *(const u64*)&htile[rr][cc];
      __hip_atomic_store((u64*)&dst[(mtile * 16 + rr) * 512 + grp * 16 + cc], v,
                         __ATOMIC_RELAXED, __HIP_MEMORY_SCOPE_AGENT);
      __builtin_amdgcn_s_waitcnt(0);  // h-stores globally complete before barrier B
    }
    __syncthreads();  // B
    if (t < 256) {
      const int ep = t + 2;  // epochs 1..257
      if (tid == 128)
        __hip_atomic_store(&slots[bid * 32], ep, __ATOMIC_RELAXED, __HIP_MEMORY_SCOPE_AGENT);
      if (tid < 128) {
        while (__hip_atomic_load(&slots[tid * 32], __ATOMIC_RELAXED,
                                 __HIP_MEMORY_SCOPE_AGENT) < ep)
          __builtin_amdgcn_s_sleep(1);
      }
      __syncthreads();  // C
    }
  }
}

// ---------------------------------------------------------------------------
extern "C" void kernel_launch(void* const* d_in, const int* in_sizes, int n_in,
                              void* d_out, int out_size, void* d_ws, size_t ws_size,
                              hipStream_t stream) {
  (void)in_sizes; (void)n_in; (void)out_size; (void)ws_size;
  const float* enc   = (const float*)d_in[0];
  const int*   lw    = (const int*)d_in[1];
  const int*   mask  = (const int*)d_in[2];
  const float* P_w   = (const float*)d_in[3];
  const float* P_b   = (const float*)d_in[4];
  const float* emb   = (const float*)d_in[5];
  const float* din_w = (const float*)d_in[6];
  const float* din_b = (const float*)d_in[7];
  const float* k0    = (const float*)d_in[8];
  const float* r0    = (const float*)d_in[9];
  const float* b0    = (const float*)d_in[10];
  const float* k1    = (const float*)d_in[11];
  const float* r1    = (const float*)d_in[12];
  const float* b1    = (const float*)d_in[13];
  float* out = (float*)d_out;

  char* base = (char*)d_ws;
  size_t off = 0;
  auto alloc = [&](size_t b) -> void* {
    void* p = base + off;
    off = (off + b + 255) & ~(size_t)255;
    return p;
  };
  float* xk0  = (float*)alloc(8192UL * 2048 * 4);   // 67 MB
  u16* encb   = (u16*)alloc(32UL * 512 * 512 * 2);
  u16* encT   = (u16*)alloc(32UL * 512 * 512 * 2);
  float* aTf  = (float*)alloc(32UL * 256 * 512 * 4);
  u16* aTb    = (u16*)alloc(32UL * 256 * 512 * 2);
  u16* pd     = (u16*)alloc(8192UL * 512 * 2);
  u16* wt_r0  = (u16*)alloc(2048UL * 512 * 2);
  u16* wt_k1  = (u16*)alloc(2048UL * 512 * 2);
  u16* wt_r1  = (u16*)alloc(2048UL * 512 * 2);
  u16* k0T    = (u16*)alloc(2048UL * 512 * 2);
  u16* PwT    = (u16*)alloc(512UL * 512 * 2);
  u16* dinwb  = (u16*)alloc(512UL * 512 * 2);
  u16* WfT    = (u16*)alloc(2048UL * 512 * 2);
  float* bfld = (float*)alloc(2048 * 4);
  u16* h0b    = (u16*)alloc(2UL * 32 * 512 * 2);
  u16* h1b    = (u16*)alloc(2UL * 32 * 512 * 2);
  int* slots  = (int*)alloc(128 * 32 * 4);          // 16 KB epoch slots

  conv_kernel<<<8192, 256, 0, stream>>>(enc, encb, 32L * 512 * 512);
  tconv_kernel<<<dim3(16, 16, 32), 256, 0, stream>>>(enc, encT, 512, 512, 262144, 262144);
  tconv_kernel<<<dim3(64, 16, 1), 256, 0, stream>>>(r0, wt_r0, 512, 2048, 0, 0);
  tconv_kernel<<<dim3(64, 16, 1), 256, 0, stream>>>(k1, wt_k1, 512, 2048, 0, 0);
  tconv_kernel<<<dim3(64, 16, 1), 256, 0, stream>>>(r1, wt_r1, 512, 2048, 0, 0);
  tconv_kernel<<<dim3(64, 16, 1), 256, 0, stream>>>(k0, k0T, 512, 2048, 0, 0);
  tconv_kernel<<<dim3(16, 16, 1), 256, 0, stream>>>(P_w, PwT, 512, 512, 0, 0);
  conv_kernel<<<256, 256, 0, stream>>>(din_w, dinwb, 512L * 512);

  // K1: py = emb[lw] @ P_w + P_b -> pd (bf16)
  gemm_bt_kernel<1, 0, true><<<dim3(4, 64, 1), 256, 0, stream>>>(
      nullptr, emb, PwT, nullptr, pd, P_b, lw, nullptr, 0,
      8192, 512, 512, 0, 0, 0, 0);
  // K5: WfT = (din_w @ k0)^T
  gemm_bt_kernel<0, 3, false><<<dim3(16, 4, 1), 256, 0, stream>>>(
      dinwb, nullptr, k0T, nullptr, WfT, nullptr, nullptr, nullptr, 0,
      512, 2048, 512, 0, 0, 0, 0);
  bfold_kernel<<<8, 256, 0, stream>>>(din_b, k0, b0, bfld);
  // K2: scores + mask
  gemm_bt_kernel<0, 2, false><<<dim3(4, 2, 32), 256, 0, stream>>>(
      pd, nullptr, encb, aTf, nullptr, nullptr, nullptr, mask, 256,
      256, 512, 512, 131072, 262144, 131072, 131072);
  softmax_kernel<<<2048, 256, 0, stream>>>(aTf, aTb);
  // K4: dec = softmax @ enc
  gemm_bt_kernel<0, 0, false><<<dim3(4, 2, 32), 256, 0, stream>>>(
      aTb, nullptr, encT, nullptr, pd, nullptr, nullptr, nullptr, 0,
      256, 512, 512, 131072, 262144, 131072, 0);
  // K6: xk0 = dec @ (din_w@k0) + folded bias
  gemm_bt_kernel<0, 1, true><<<dim3(16, 64, 1), 256, 0, stream>>>(
      pd, nullptr, WfT, xk0, nullptr, bfld, nullptr, nullptr, 0,
      8192, 2048, 512, 0, 0, 0, 0);

  // slots -> 0 (belt & braces; 0xAA poison is negative and also safe)
  hipMemsetAsync(slots, 0, 128 * 32 * 4, stream);
  lstm_kernel<<<128, 256, 0, stream>>>(wt_r0, wt_k1, wt_r1, xk0, b1, h0b, h1b, out, slots);
}